// Round 7
// baseline (464.129 us; speedup 1.0000x reference)
//
#include <hip/hip_runtime.h>
#include <cstdint>
#include <cstddef>

#define H 64
#define C 7
#define F 20
#define BSH 9
#define BSZ 512
#define CH 8192

typedef unsigned short u16;
typedef __attribute__((ext_vector_type(8))) short bf16x8;
typedef __attribute__((ext_vector_type(4))) float f32x4;
typedef __attribute__((ext_vector_type(2))) float f32x2;

static __device__ __forceinline__ int imax(int a, int b) { return a > b ? a : b; }
static __device__ __forceinline__ int imin(int a, int b) { return a < b ? a : b; }

static __device__ __forceinline__ float bf2f(u16 v) {
  union { unsigned u; float f; } x; x.u = ((unsigned)v) << 16; return x.f;
}
static __device__ __forceinline__ u16 f2bf(float f) {  // round-nearest-even
  union { float f; unsigned u; } x; x.f = f;
  unsigned r = x.u + 0x7fffu + ((x.u >> 16) & 1u);
  return (u16)(r >> 16);
}
static __device__ __forceinline__ int pack2bf(float a, float b) {
  return (int)f2bf(a) | ((int)f2bf(b) << 16);
}
static __device__ __forceinline__ float lo16f(unsigned v) {
  union { unsigned u; float f; } x; x.u = v << 16; return x.f;
}
static __device__ __forceinline__ float hi16f(unsigned v) {
  union { unsigned u; float f; } x; x.u = v & 0xffff0000u; return x.f;
}
static __device__ __forceinline__ int cvtpk_bf16(float a, float b) {
  int w;
  asm("v_cvt_pk_bf16_f32 %0, %1, %2" : "=v"(w) : "v"(a), "v"(b));
  return w;
}

// ---------- phase 1: coarse bucket histogram ----------
__global__ __launch_bounds__(256) void k_bhist(const int* __restrict__ esrc,
                                               const int* __restrict__ edst, int E,
                                               int* __restrict__ gcnt_u, int* __restrict__ gcnt_m,
                                               int nbu, int nbm) {
  extern __shared__ int sh[];
  int* hu = sh;
  int* hm = sh + nbu;
  for (int i = threadIdx.x; i < nbu + nbm; i += 256) sh[i] = 0;
  __syncthreads();
  int stride = gridDim.x * 256;
  for (int i = blockIdx.x * 256 + threadIdx.x; i < E; i += stride) {
    atomicAdd(&hu[esrc[i] >> BSH], 1);
    atomicAdd(&hm[edst[i] >> BSH], 1);
  }
  __syncthreads();
  for (int i = threadIdx.x; i < nbu; i += 256) if (hu[i]) atomicAdd(&gcnt_u[i], hu[i]);
  for (int i = threadIdx.x; i < nbm; i += 256) if (hm[i]) atomicAdd(&gcnt_m[i], hm[i]);
}

// ---------- phase 2: scan bucket counts ----------
__global__ __launch_bounds__(256) void k_bscan(const int* __restrict__ gcnt_u,
                                               const int* __restrict__ gcnt_m,
                                               int nbu, int nbm, int E,
                                               int* __restrict__ boff_u, int* __restrict__ boff_m,
                                               int* __restrict__ gcur_u, int* __restrict__ gcur_m) {
  __shared__ int s[1024];
  for (int i = threadIdx.x; i < nbu; i += 256) s[i] = gcnt_u[i];
  for (int i = threadIdx.x; i < nbm; i += 256) s[512 + i] = gcnt_m[i];
  __syncthreads();
  if (threadIdx.x == 0) {
    int r = 0;
    for (int i = 0; i < nbu; ++i) { int v = s[i]; s[i] = r; r += v; }
  }
  if (threadIdx.x == 1) {
    int r = 0;
    for (int i = 0; i < nbm; ++i) { int v = s[512 + i]; s[512 + i] = r; r += v; }
  }
  __syncthreads();
  for (int i = threadIdx.x; i < nbu; i += 256) { boff_u[i] = s[i]; gcur_u[i] = s[i]; }
  for (int i = threadIdx.x; i < nbm; i += 256) { boff_m[i] = s[512 + i]; gcur_m[i] = s[512 + i]; }
  if (threadIdx.x == 0) { boff_u[nbu] = E; boff_m[nbm] = E; }
}

// ---------- phase 3: binning scatter into coarse buckets ----------
__global__ __launch_bounds__(256) void k_bscat(const int* __restrict__ esrc,
                                               const int* __restrict__ edst, int E,
                                               int* __restrict__ gcur_u, int* __restrict__ gcur_m,
                                               unsigned int* __restrict__ pk_u,
                                               unsigned int* __restrict__ pk_m,
                                               int nbu, int nbm, int nchunks) {
  extern __shared__ int sh2[];
  int dir = (blockIdx.x >= (unsigned)nchunks) ? 1 : 0;
  int chunk = dir ? (blockIdx.x - nchunks) : blockIdx.x;
  const int* key = dir ? edst : esrc;
  const int* pay = dir ? esrc : edst;
  int* gcur = dir ? gcur_m : gcur_u;
  unsigned int* pk = dir ? pk_m : pk_u;
  int nb = dir ? nbm : nbu;
  int* cnt = sh2;
  int* base = sh2 + nb;
  int beg = chunk * CH;
  int end = imin(beg + CH, E);
  for (int i = threadIdx.x; i < nb; i += 256) cnt[i] = 0;
  __syncthreads();
  for (int i = beg + threadIdx.x; i < end; i += 256) atomicAdd(&cnt[key[i] >> BSH], 1);
  __syncthreads();
  for (int i = threadIdx.x; i < nb; i += 256) {
    int c = cnt[i];
    base[i] = c ? atomicAdd(&gcur[i], c) : 0;
    cnt[i] = 0;
  }
  __syncthreads();
  for (int i = beg + threadIdx.x; i < end; i += 256) {
    int k = key[i];
    int b = k >> BSH;
    int r = atomicAdd(&cnt[b], 1);
    pk[base[b] + r] = ((unsigned)(k & (BSZ - 1)) << 18) | (unsigned)pay[i];
  }
}

// ---------- phase 4: per-bucket CSR build ----------
__global__ __launch_bounds__(512) void k_bbuild(const unsigned int* __restrict__ pk_u,
                                                const unsigned int* __restrict__ pk_m,
                                                const int* __restrict__ boff_u,
                                                const int* __restrict__ boff_m,
                                                int nbu, int nbm, int U_, int M_, int E,
                                                int* __restrict__ csr_u, int* __restrict__ csr_m,
                                                int* __restrict__ off_u, int* __restrict__ off_m) {
  __shared__ int hist[BSZ];
  __shared__ int cur[BSZ];
  int dir = (blockIdx.x >= (unsigned)nbu) ? 1 : 0;
  int b = dir ? (blockIdx.x - nbu) : blockIdx.x;
  const unsigned int* pk = dir ? pk_m : pk_u;
  const int* boff = dir ? boff_m : boff_u;
  int N = dir ? M_ : U_;
  int nb = dir ? nbm : nbu;
  int* csr = dir ? csr_m : csr_u;
  int* off = dir ? off_m : off_u;
  int beg = boff[b], end = boff[b + 1];
  int t = threadIdx.x;
  hist[t] = 0;
  __syncthreads();
  for (int i = beg + t; i < end; i += 512) atomicAdd(&hist[pk[i] >> 18], 1);
  __syncthreads();
  int v0 = hist[t];
  for (int o = 1; o < 512; o <<= 1) {
    int x = (t >= o) ? hist[t - o] : 0;
    __syncthreads();
    hist[t] += x;
    __syncthreads();
  }
  int excl = hist[t] - v0;
  cur[t] = excl;
  int node = (b << BSH) + t;
  if (node < N) off[node] = beg + excl;
  if (t == 0 && b == nb - 1) off[N] = E;
  __syncthreads();
  for (int i = beg + t; i < end; i += 512) {
    unsigned int p = pk[i];
    int n = (int)(p >> 18);
    int r = atomicAdd(&cur[n], 1);
    csr[beg + r] = (int)(p & 0x3FFFFu);
  }
}

// ---------- merged prep: movie projection + user cvt + combined classifier weights ----------
__global__ __launch_bounds__(256) void k_prep(
    const float* __restrict__ movie_x, const float* __restrict__ w_movie,
    const float* __restrict__ b_movie, const float* __restrict__ movie_emb,
    const int* __restrict__ mnid,
    const float* __restrict__ user_emb, const int* __restrict__ unid,
    const float* __restrict__ l2u_Wl, const float* __restrict__ l2u_Wr,
    const float* __restrict__ l2u_bl,
    const float* __restrict__ l2m_Wl, const float* __restrict__ l2m_Wr,
    const float* __restrict__ l2m_bl,
    const float* __restrict__ clsW,
    u16* __restrict__ xm_bf, u16* __restrict__ xu_bf, float* __restrict__ cw,
    int M_, int U_, int gProj, int gCvt) {
  __shared__ float ws_[F * H];
  int b = blockIdx.x;
  if (b < gProj) {
    for (int i = threadIdx.x; i < F * H; i += 256) ws_[i] = w_movie[i];
    __syncthreads();
    int t = b * 256 + threadIdx.x;
    int m = t >> 6;
    int h = t & 63;
    if (m >= M_) return;
    float acc = b_movie[h] + movie_emb[(size_t)mnid[m] * H + h];
    const float* xr = movie_x + (size_t)m * F;
    #pragma unroll
    for (int f = 0; f < F; ++f) acc += xr[f] * ws_[f * H + h];
    xm_bf[(size_t)m * H + h] = f2bf(acc);
  } else if (b < gProj + gCvt) {
    int t = (b - gProj) * 256 + threadIdx.x;
    if (t >= U_ * 16) return;
    int i = t >> 4;
    int g = t & 15;
    const float4 v = *(const float4*)(user_emb + (size_t)unid[i] * H + g * 4);
    ushort4 o;
    o.x = f2bf(v.x); o.y = f2bf(v.y); o.z = f2bf(v.z); o.w = f2bf(v.w);
    *(ushort4*)(xu_bf + (size_t)i * H + g * 4) = o;
  } else {
    int t = (b - gProj - gCvt) * 256 + threadIdx.x;
    if (t < 448) {
      int k = t / C, c = t % C;
      float s = 0.f;
      for (int j = 0; j < H; ++j) s += l2u_Wl[k * H + j] * clsW[j * C + c];
      cw[t] = s;
    } else if (t < 896) {
      int u = t - 448; int k = u / C, c = u % C;
      float s = 0.f;
      for (int j = 0; j < H; ++j) s += l2u_Wr[k * H + j] * clsW[j * C + c];
      cw[t] = s;
    } else if (t < 1344) {
      int u = t - 896; int k = u / C, c = u % C;
      float s = 0.f;
      for (int j = 0; j < H; ++j) s += l2m_Wl[k * H + j] * clsW[(H + j) * C + c];
      cw[t] = s;
    } else if (t < 1792) {
      int u = t - 1344; int k = u / C, c = u % C;
      float s = 0.f;
      for (int j = 0; j < H; ++j) s += l2m_Wr[k * H + j] * clsW[(H + j) * C + c];
      cw[t] = s;
    } else if (t < 1799) {
      int c = t - 1792;
      float s = 0.f;
      for (int j = 0; j < H; ++j) s += l2u_bl[j] * clsW[j * C + c];
      cw[t] = s;
    } else if (t < 1806) {
      int c = t - 1799;
      float s = 0.f;
      for (int j = 0; j < H; ++j) s += l2m_bl[j] * clsW[(H + j) * C + c];
      cw[t] = s;
    } else if (t < 1870) {
      // zero row appended to movie bf16 table (index M_): out-of-range gather target
      xm_bf[(size_t)M_ * H + (t - 1806)] = 0;
    } else if (t < 1934) {
      // zero row appended to user bf16 table (index U_)
      xu_bf[(size_t)U_ * H + (t - 1870)] = 0;
    }
  }
}

// ---------- merged fused SAGE layer-1 (MFMA transform) + classifier projection ----------
// R6-proven config: LDS 57,856 (2 blocks/CU), launch_bounds(512,4), VGPR budget 128.
// R7: the two 8-node gather groups are MERGED into one loop -> 16 row loads in
// flight per iteration (2x memory-level parallelism, half the shfl sync points).
// Latency-bound kernel (VALUBusy 37%, occupancy LDS-capped): MLP is the only lever.
__global__ __launch_bounds__(512, 4) void k_sage_mfma(
    const u16* __restrict__ xu, const u16* __restrict__ xm,
    const int* __restrict__ csr_u, const int* __restrict__ off_u,
    const int* __restrict__ csr_m, const int* __restrict__ off_m,
    const float* __restrict__ WlU, const float* __restrict__ blU, const float* __restrict__ WrU,
    const float* __restrict__ WlM, const float* __restrict__ blM, const float* __restrict__ WrM,
    const float* __restrict__ CWml, const float* __restrict__ CWur,   // user-side Z parts
    const float* __restrict__ CWul, const float* __restrict__ CWmr,   // movie-side Z parts
    u16* __restrict__ Zau, u16* __restrict__ Zru,
    u16* __restrict__ Zam, u16* __restrict__ Zrm,
    int U_, int M_, int E_, int gU) {
  __shared__ int sWl[64 * 36];
  __shared__ int sWr[64 * 36];
  __shared__ int sAggHi[128 * 36];
  __shared__ int sAggLo[128 * 36];
  __shared__ int sCC[16 * 36];
  __shared__ float sBl[64];

  int movie = (blockIdx.x >= (unsigned)gU) ? 1 : 0;
  int bside = movie ? (blockIdx.x - gU) : blockIdx.x;
  const u16* srcT = movie ? xu : xm;
  const u16* rootT = movie ? xm : xu;
  const int* csr = movie ? csr_m : csr_u;
  const int* off = movie ? off_m : off_u;
  const float* Wl = movie ? WlM : WlU;
  const float* Wr = movie ? WrM : WrU;
  const float* bl = movie ? blM : blU;
  const float* CWl = movie ? CWul : CWml;
  const float* CWr = movie ? CWmr : CWur;
  u16* Za = movie ? Zam : Zau;
  u16* Zr = movie ? Zrm : Zru;
  int N = movie ? M_ : U_;
  int zrow = movie ? U_ : M_;        // index of the all-zero row in srcT

  int tid = threadIdx.x;
  // stage weights: W^T as bf16 pairs (row j, 32 dwords + 4 pad)
  for (int idx = tid; idx < 2048; idx += 512) {
    int j = idx & 63, kk = idx >> 6;
    sWl[j * 36 + kk] = pack2bf(Wl[(2 * kk) * H + j], Wl[(2 * kk + 1) * H + j]);
    sWr[j * 36 + kk] = pack2bf(Wr[(2 * kk) * H + j], Wr[(2 * kk + 1) * H + j]);
  }
  // stage combined classifier matrix CC[j][cc] (bf16 pairs along j), B-fragment layout
  for (int idx = tid; idx < 512; idx += 512) {
    int cc = idx >> 5, kk = idx & 31;
    float f0, f1;
    if (cc < 7)       { f0 = CWl[(2 * kk) * C + cc];     f1 = CWl[(2 * kk + 1) * C + cc]; }
    else if (cc == 7) { f0 = 0.f; f1 = 0.f; }
    else if (cc < 15) { f0 = CWr[(2 * kk) * C + cc - 8]; f1 = CWr[(2 * kk + 1) * C + cc - 8]; }
    else              { f0 = 0.f; f1 = 0.f; }
    sCC[cc * 36 + kk] = pack2bf(f0, f1);
  }
  if (tid < 64) sBl[tid] = bl[tid];
  __syncthreads();

  int lane = tid & 63;
  int wid = tid >> 6;
  int slot = lane >> 3;      // 0..7: node within group
  int l3 = lane & 7;         // 0..7: column-octet within row
  int sbase = slot * 8;
  int node0 = bside * 128 + wid * 16;

  // ---- merged gather: both 8-node groups in ONE loop (16 rows in flight) ----
  int n0 = node0 + slot;
  int n1 = node0 + 8 + slot;
  int nc0 = n0 < N ? n0 : N - 1;
  int nc1 = n1 < N ? n1 : N - 1;
  int jb0 = off[nc0];
  int d0 = off[nc0 + 1] - jb0;
  if (n0 >= N) d0 = 0;
  int jb1 = off[nc1];
  int d1 = off[nc1 + 1] - jb1;
  if (n1 >= N) d1 = 0;
  int dm = imax(d0, d1);
  dm = imax(dm, __shfl_xor(dm, 8));
  dm = imax(dm, __shfl_xor(dm, 16));
  dm = imax(dm, __shfl_xor(dm, 32));

  f32x2 acc0[4] = {{0.f, 0.f}, {0.f, 0.f}, {0.f, 0.f}, {0.f, 0.f}};
  f32x2 acc1[4] = {{0.f, 0.f}, {0.f, 0.f}, {0.f, 0.f}, {0.f, 0.f}};
  for (int tb = 0; tb < dm; tb += 8) {
    int idx = tb + l3;
    int e0 = (idx < d0) ? csr[imin(jb0 + idx, E_ - 1)] : zrow;
    int e1 = (idx < d1) ? csr[imin(jb1 + idx, E_ - 1)] : zrow;
    uint4 v0[8], v1[8];
    #pragma unroll
    for (int k = 0; k < 8; ++k) {
      int a = __shfl(e0, sbase + k);
      v0[k] = *(const uint4*)(srcT + (size_t)(unsigned)a * H + l3 * 8);
    }
    #pragma unroll
    for (int k = 0; k < 8; ++k) {
      int a = __shfl(e1, sbase + k);
      v1[k] = *(const uint4*)(srcT + (size_t)(unsigned)a * H + l3 * 8);
    }
    #pragma unroll
    for (int k = 0; k < 8; ++k) {
      f32x2 p0 = {lo16f(v0[k].x), hi16f(v0[k].x)};
      f32x2 p1 = {lo16f(v0[k].y), hi16f(v0[k].y)};
      f32x2 p2 = {lo16f(v0[k].z), hi16f(v0[k].z)};
      f32x2 p3 = {lo16f(v0[k].w), hi16f(v0[k].w)};
      acc0[0] += p0; acc0[1] += p1; acc0[2] += p2; acc0[3] += p3;
      f32x2 q0 = {lo16f(v1[k].x), hi16f(v1[k].x)};
      f32x2 q1 = {lo16f(v1[k].y), hi16f(v1[k].y)};
      f32x2 q2 = {lo16f(v1[k].z), hi16f(v1[k].z)};
      f32x2 q3 = {lo16f(v1[k].w), hi16f(v1[k].w)};
      acc1[0] += q0; acc1[1] += q1; acc1[2] += q2; acc1[3] += q3;
    }
  }

  // finalize both groups: mean, hi/lo bf16 split via v_cvt_pk, b128 LDS store
  #pragma unroll
  for (int g = 0; g < 2; ++g) {
    f32x2* ac = g ? acc1 : acc0;
    int dd = g ? d1 : d0;
    float inv = 1.0f / (float)imax(dd, 1);
    int hi4[4], lo4[4];
    #pragma unroll
    for (int pp = 0; pp < 4; ++pp) {
      float s0 = ac[pp].x * inv;
      float s1 = ac[pp].y * inv;
      int w = cvtpk_bf16(s0, s1);
      float r0 = s0 - lo16f((unsigned)w);
      float r1 = s1 - hi16f((unsigned)w);
      hi4[pp] = w;
      lo4[pp] = cvtpk_bf16(r0, r1);
    }
    int row = wid * 16 + g * 8 + slot;
    *(int4*)&sAggHi[row * 36 + l3 * 4] = *(int4*)hi4;
    *(int4*)&sAggLo[row * 36 + l3 * 4] = *(int4*)lo4;
  }
  // per-wave region: wave reads only its own writes; in-wave LDS ordering suffices

  // ---- MFMA transform phase ----
  int r16 = lane & 15;
  int q4 = lane >> 4;
  union FU { int4 i; bf16x8 b; };
  FU ahi[2], alo[2], art[2];
  int arow = wid * 16 + r16;
  int rnode = node0 + r16;
  rnode = rnode < N ? rnode : N - 1;
  #pragma unroll
  for (int kt = 0; kt < 2; ++kt) {
    ahi[kt].i = *(const int4*)&sAggHi[arow * 36 + kt * 16 + q4 * 4];
    alo[kt].i = *(const int4*)&sAggLo[arow * 36 + kt * 16 + q4 * 4];
    art[kt].i = ((const int4*)(rootT + (size_t)rnode * H))[kt * 4 + q4];
  }

  // sAggHi rows of THIS wave are dead once ahi/alo are in registers: reuse them as the
  // relayout buffer valT[16 nodes][64 j] (u16, row stride 72 = 36 dwords, 2-way banks).
  u16* sVT = (u16*)(sAggHi + (size_t)wid * 16 * 36);
  const int* sVTd = sAggHi + (size_t)wid * 16 * 36;

  #pragma unroll
  for (int t = 0; t < 4; ++t) {
    f32x4 cacc = {0.f, 0.f, 0.f, 0.f};
    #pragma unroll
    for (int kt = 0; kt < 2; ++kt) {
      FU bwl, bwr;
      bwl.i = *(const int4*)&sWl[(t * 16 + r16) * 36 + kt * 16 + q4 * 4];
      bwr.i = *(const int4*)&sWr[(t * 16 + r16) * 36 + kt * 16 + q4 * 4];
      cacc = __builtin_amdgcn_mfma_f32_16x16x32_bf16(ahi[kt].b, bwl.b, cacc, 0, 0, 0);
      cacc = __builtin_amdgcn_mfma_f32_16x16x32_bf16(alo[kt].b, bwl.b, cacc, 0, 0, 0);
      cacc = __builtin_amdgcn_mfma_f32_16x16x32_bf16(art[kt].b, bwr.b, cacc, 0, 0, 0);
    }
    float bj = sBl[t * 16 + r16];
    float v0 = fmaxf(cacc[0] + bj, 0.f);
    float v1 = fmaxf(cacc[1] + bj, 0.f);
    float v2 = fmaxf(cacc[2] + bj, 0.f);
    float v3 = fmaxf(cacc[3] + bj, 0.f);
    // relu'd H_out[node=q4*4+r][j=t*16+r16] -> valT[node][j] (A-fragment layout)
    int w01 = cvtpk_bf16(v0, v1);
    int w23 = cvtpk_bf16(v2, v3);
    int base = (q4 * 4) * 72 + t * 16 + r16;
    sVT[base]       = (u16)w01;
    sVT[base + 72]  = (u16)((unsigned)w01 >> 16);
    sVT[base + 144] = (u16)w23;
    sVT[base + 216] = (u16)((unsigned)w23 >> 16);
  }

  // ---- classifier projection as a second MFMA: Z[16 nodes][16 cc] = valT @ CC ----
  f32x4 z4 = {0.f, 0.f, 0.f, 0.f};
  #pragma unroll
  for (int kt = 0; kt < 2; ++kt) {
    FU a2, b2;
    a2.i = *(const int4*)&sVTd[r16 * 36 + kt * 16 + q4 * 4];
    b2.i = *(const int4*)&sCC[r16 * 36 + kt * 16 + q4 * 4];
    z4 = __builtin_amdgcn_mfma_f32_16x16x32_bf16(a2.b, b2.b, z4, 0, 0, 0);
  }

  // ---- coalesced split-Z write: transpose through LDS (this wave's sAggLo is dead)
  // ztile[16 nodes][16 cc] u16; lanes 0..15 store Za rows (int4), 16..31 store Zr.
  u16* zt = (u16*)(sAggLo + (size_t)wid * 16 * 36);
  #pragma unroll
  for (int r = 0; r < 4; ++r) zt[(q4 * 4 + r) * 16 + r16] = f2bf(z4[r]);
  if (lane < 32) {
    int nodeL = lane & 15;
    int half = lane >> 4;          // 0: Za (cols 0..7), 1: Zr (cols 8..15)
    int node = node0 + nodeL;
    if (node < N) {
      int4 zi = *(const int4*)&zt[nodeL * 16 + half * 8];
      u16* Zq = half ? Zr : Za;
      *(int4*)&Zq[(size_t)node * 8] = zi;
    }
  }
}

// ---------- merged layer-2 aggregation in projected bf16 space ----------
// Z split into 16 B aggregate/root rows halves the random-gather volume.
static __device__ __forceinline__ void accz8(float* acc, uint4 zv) {
  acc[0] += lo16f(zv.x); acc[1] += hi16f(zv.x);
  acc[2] += lo16f(zv.y); acc[3] += hi16f(zv.y);
  acc[4] += lo16f(zv.z); acc[5] += hi16f(zv.z);
  acc[6] += lo16f(zv.w); acc[7] += hi16f(zv.w);
}

__global__ __launch_bounds__(256) void k_agg7m(
    const u16* __restrict__ Zau, const u16* __restrict__ Zru,
    const u16* __restrict__ Zam, const u16* __restrict__ Zrm,
    const int* __restrict__ csr_u, const int* __restrict__ off_u,
    const int* __restrict__ csr_m, const int* __restrict__ off_m,
    const float* __restrict__ cbu, const float* __restrict__ cbm,
    float* __restrict__ Pu, float* __restrict__ Pm,
    int U_, int M_, int gU) {
  int movie = (blockIdx.x >= (unsigned)gU) ? 1 : 0;
  int bside = movie ? (blockIdx.x - gU) : blockIdx.x;
  const u16* Zsrc = movie ? Zau : Zam;   // aggregate part of opposite side
  const u16* Zroot = movie ? Zrm : Zru;  // root part of own side
  const int* csr = movie ? csr_m : csr_u;
  const int* off = movie ? off_m : off_u;
  const float* cb = movie ? cbm : cbu;
  float* P = movie ? Pm : Pu;
  int N = movie ? M_ : U_;

  int n = bside * 256 + threadIdx.x;
  if (n >= N) return;
  int beg = off[n], end = off[n + 1];
  float acc[8] = {0.f, 0.f, 0.f, 0.f, 0.f, 0.f, 0.f, 0.f};
  int j = beg;
  for (; j + 4 <= end; j += 4) {
    int a0 = csr[j], a1 = csr[j + 1], a2 = csr[j + 2], a3 = csr[j + 3];
    uint4 z0 = *(const uint4*)(Zsrc + (size_t)a0 * 8);
    uint4 z1 = *(const uint4*)(Zsrc + (size_t)a1 * 8);
    uint4 z2 = *(const uint4*)(Zsrc + (size_t)a2 * 8);
    uint4 z3 = *(const uint4*)(Zsrc + (size_t)a3 * 8);
    accz8(acc, z0); accz8(acc, z1); accz8(acc, z2); accz8(acc, z3);
  }
  for (; j < end; ++j) {
    uint4 zv = *(const uint4*)(Zsrc + (size_t)csr[j] * 8);
    accz8(acc, zv);
  }
  float inv = 1.f / (float)imax(end - beg, 1);
  uint4 zr = *(const uint4*)(Zroot + (size_t)n * 8);
  float4 o0, o1;
  o0.x = acc[0] * inv + lo16f(zr.x) + cb[0];
  o0.y = acc[1] * inv + hi16f(zr.x) + cb[1];
  o0.z = acc[2] * inv + lo16f(zr.y) + cb[2];
  o0.w = acc[3] * inv + hi16f(zr.y) + cb[3];
  o1.x = acc[4] * inv + lo16f(zr.z) + cb[4];
  o1.y = acc[5] * inv + hi16f(zr.z) + cb[5];
  o1.z = acc[6] * inv + lo16f(zr.w) + cb[6];
  o1.w = 0.f;
  float4* po = (float4*)(P + (size_t)n * 8);
  po[0] = o0;
  po[1] = o1;
}

// ---------- final edge classifier: one thread per edge ----------
__global__ __launch_bounds__(256) void k_final(const int* __restrict__ els,
                                               const int* __restrict__ eld,
                                               const float* __restrict__ Pu,
                                               const float* __restrict__ Pm,
                                               const float* __restrict__ clsb,
                                               float* __restrict__ out, int EL_) {
  int e = blockIdx.x * 256 + threadIdx.x;
  if (e >= EL_) return;
  int su = els[e], sm = eld[e];
  const float4* pu = (const float4*)(Pu + (size_t)su * 8);
  const float4* pm = (const float4*)(Pm + (size_t)sm * 8);
  float4 u0 = pu[0], u1 = pu[1];
  float4 m0 = pm[0], m1 = pm[1];
  float* po = out + (size_t)e * C;
  po[0] = u0.x + m0.x + clsb[0];
  po[1] = u0.y + m0.y + clsb[1];
  po[2] = u0.z + m0.z + clsb[2];
  po[3] = u0.w + m0.w + clsb[3];
  po[4] = u1.x + m1.x + clsb[4];
  po[5] = u1.y + m1.y + clsb[5];
  po[6] = u1.z + m1.z + clsb[6];
}

extern "C" void kernel_launch(void* const* d_in, const int* in_sizes, int n_in,
                              void* d_out, int out_size, void* d_ws, size_t ws_size,
                              hipStream_t stream) {
  (void)n_in; (void)out_size; (void)ws_size;
  const int*   unid      = (const int*)d_in[0];
  const int*   mnid      = (const int*)d_in[1];
  const float* movie_x   = (const float*)d_in[2];
  const int*   e_src     = (const int*)d_in[3];
  const int*   e_dst     = (const int*)d_in[4];
  const int*   el_src    = (const int*)d_in[5];
  const int*   el_dst    = (const int*)d_in[6];
  const float* user_emb  = (const float*)d_in[7];
  const float* movie_emb = (const float*)d_in[8];
  const float* w_movie   = (const float*)d_in[9];
  const float* b_movie   = (const float*)d_in[10];
  const float* l1r_Wl    = (const float*)d_in[11];
  const float* l1r_bl    = (const float*)d_in[12];
  const float* l1r_Wr    = (const float*)d_in[13];
  const float* l1v_Wl    = (const float*)d_in[14];
  const float* l1v_bl    = (const float*)d_in[15];
  const float* l1v_Wr    = (const float*)d_in[16];
  const float* l2r_Wl    = (const float*)d_in[17];
  const float* l2r_bl    = (const float*)d_in[18];
  const float* l2r_Wr    = (const float*)d_in[19];
  const float* l2v_Wl    = (const float*)d_in[20];
  const float* l2v_bl    = (const float*)d_in[21];
  const float* l2v_Wr    = (const float*)d_in[22];
  const float* cls_W     = (const float*)d_in[23];
  const float* cls_b     = (const float*)d_in[24];

  int U  = in_sizes[0];
  int M  = in_sizes[1];
  int E  = in_sizes[3];
  int EL = in_sizes[5];

  int nbu = (U + BSZ - 1) / BSZ;
  int nbm = (M + BSZ - 1) / BSZ;
  int nchunks = (E + CH - 1) / CH;

  char* p = (char*)d_ws;
  auto alloc = [&](size_t nbytes) { char* r = p; p += (nbytes + 255) & ~(size_t)255; return r; };

  u16*   xm_bf  = (u16*)alloc((size_t)(M + 1) * H * 2);   // +1: zero row for invalid gathers
  u16*   xu_bf  = (u16*)alloc((size_t)(U + 1) * H * 2);   // +1: zero row
  u16*   Zau    = (u16*)alloc((size_t)U * 8 * 2);
  u16*   Zru    = (u16*)alloc((size_t)U * 8 * 2);
  u16*   Zam    = (u16*)alloc((size_t)M * 8 * 2);
  u16*   Zrm    = (u16*)alloc((size_t)M * 8 * 2);
  float* Pu     = (float*)alloc((size_t)U * 8 * 4);
  float* Pm     = (float*)alloc((size_t)M * 8 * 4);
  int*   csr_u  = (int*)alloc((size_t)E * 4);
  int*   csr_m  = (int*)alloc((size_t)E * 4);
  int*   off_u  = (int*)alloc((size_t)(U + 1) * 4);
  int*   off_m  = (int*)alloc((size_t)(M + 1) * 4);
  unsigned int* pk_u = (unsigned int*)alloc((size_t)E * 4);
  unsigned int* pk_m = (unsigned int*)alloc((size_t)E * 4);
  int*   gcnt   = (int*)alloc((size_t)(nbu + nbm) * 4);
  int*   gcnt_u = gcnt;
  int*   gcnt_m = gcnt + nbu;
  int*   boff_u = (int*)alloc((size_t)(nbu + 1) * 4);
  int*   boff_m = (int*)alloc((size_t)(nbm + 1) * 4);
  int*   gcur_u = (int*)alloc((size_t)nbu * 4);
  int*   gcur_m = (int*)alloc((size_t)nbm * 4);
  float* cw     = (float*)alloc(1806 * 4);
  float* CWul = cw, *CWur = cw + 448, *CWml = cw + 896, *CWmr = cw + 1344;
  float* cbu  = cw + 1792, *cbm = cw + 1799;

  hipMemsetAsync(gcnt, 0, (size_t)(nbu + nbm) * 4, stream);

  // ---- CSR build ----
  k_bhist<<<256, 256, (size_t)(nbu + nbm) * 4, stream>>>(e_src, e_dst, E, gcnt_u, gcnt_m, nbu, nbm);
  k_bscan<<<1, 256, 0, stream>>>(gcnt_u, gcnt_m, nbu, nbm, E, boff_u, boff_m, gcur_u, gcur_m);
  k_bscat<<<2 * nchunks, 256, (size_t)(2 * nbu) * 4, stream>>>(e_src, e_dst, E, gcur_u, gcur_m,
                                                               pk_u, pk_m, nbu, nbm, nchunks);
  k_bbuild<<<nbu + nbm, 512, 0, stream>>>(pk_u, pk_m, boff_u, boff_m, nbu, nbm, U, M, E,
                                          csr_u, csr_m, off_u, off_m);

  // ---- merged prep (bf16 tables + zero rows + combined classifier weights) ----
  int gProj = (M * H + 255) / 256;
  int gCvt  = (U * 16 + 255) / 256;
  k_prep<<<gProj + gCvt + 8, 256, 0, stream>>>(
      movie_x, w_movie, b_movie, movie_emb, mnid, user_emb, unid,
      l2v_Wl, l2v_Wr, l2v_bl, l2r_Wl, l2r_Wr, l2r_bl, cls_W,
      xm_bf, xu_bf, cw, M, U, gProj, gCvt);

  // ---- merged layer-1 (MFMA) fused with classifier projection ----
  int gU_s = (U + 127) / 128;
  int gM_s = (M + 127) / 128;
  k_sage_mfma<<<gU_s + gM_s, 512, 0, stream>>>(
      xu_bf, xm_bf, csr_u, off_u, csr_m, off_m,
      l1v_Wl, l1v_bl, l1v_Wr,
      l1r_Wl, l1r_bl, l1r_Wr,
      CWml, CWur, CWul, CWmr,
      Zau, Zru, Zam, Zrm, U, M, E, gU_s);

  // ---- merged layer-2 aggregation ----
  int gU_a = (U + 255) / 256;
  int gM_a = (M + 255) / 256;
  k_agg7m<<<gU_a + gM_a, 256, 0, stream>>>(Zau, Zru, Zam, Zrm, csr_u, off_u, csr_m, off_m,
                                           cbu, cbm, Pu, Pm, U, M, gU_a);

  // ---- final ----
  k_final<<<(EL + 255) / 256, 256, 0, stream>>>(el_src, el_dst, Pu, Pm, cls_b, (float*)d_out, EL);
}

// Round 8
// 441.078 us; speedup vs baseline: 1.0523x; 1.0523x over previous
//
#include <hip/hip_runtime.h>
#include <cstdint>
#include <cstddef>

#define H 64
#define C 7
#define F 20
#define BSH 9
#define BSZ 512
#define CH 8192
#define PBP 2048
#define PBC 1024

typedef unsigned short u16;
typedef __attribute__((ext_vector_type(8))) short bf16x8;
typedef __attribute__((ext_vector_type(4))) float f32x4;
typedef __attribute__((ext_vector_type(2))) float f32x2;

static __device__ __forceinline__ int imax(int a, int b) { return a > b ? a : b; }
static __device__ __forceinline__ int imin(int a, int b) { return a < b ? a : b; }

static __device__ __forceinline__ float bf2f(u16 v) {
  union { unsigned u; float f; } x; x.u = ((unsigned)v) << 16; return x.f;
}
static __device__ __forceinline__ u16 f2bf(float f) {  // round-nearest-even
  union { float f; unsigned u; } x; x.f = f;
  unsigned r = x.u + 0x7fffu + ((x.u >> 16) & 1u);
  return (u16)(r >> 16);
}
static __device__ __forceinline__ int pack2bf(float a, float b) {
  return (int)f2bf(a) | ((int)f2bf(b) << 16);
}
static __device__ __forceinline__ float lo16f(unsigned v) {
  union { unsigned u; float f; } x; x.u = v << 16; return x.f;
}
static __device__ __forceinline__ float hi16f(unsigned v) {
  union { unsigned u; float f; } x; x.u = v & 0xffff0000u; return x.f;
}
static __device__ __forceinline__ int cvtpk_bf16(float a, float b) {
  int w;
  asm("v_cvt_pk_bf16_f32 %0, %1, %2" : "=v"(w) : "v"(a), "v"(b));
  return w;
}

// ---------- phase 1: coarse bucket histogram ----------
__global__ __launch_bounds__(256) void k_bhist(const int* __restrict__ esrc,
                                               const int* __restrict__ edst, int E,
                                               int* __restrict__ gcnt_u, int* __restrict__ gcnt_m,
                                               int nbu, int nbm) {
  extern __shared__ int sh[];
  int* hu = sh;
  int* hm = sh + nbu;
  for (int i = threadIdx.x; i < nbu + nbm; i += 256) sh[i] = 0;
  __syncthreads();
  int stride = gridDim.x * 256;
  for (int i = blockIdx.x * 256 + threadIdx.x; i < E; i += stride) {
    atomicAdd(&hu[esrc[i] >> BSH], 1);
    atomicAdd(&hm[edst[i] >> BSH], 1);
  }
  __syncthreads();
  for (int i = threadIdx.x; i < nbu; i += 256) if (hu[i]) atomicAdd(&gcnt_u[i], hu[i]);
  for (int i = threadIdx.x; i < nbm; i += 256) if (hm[i]) atomicAdd(&gcnt_m[i], hm[i]);
}

// ---------- phase 2: scan bucket counts ----------
__global__ __launch_bounds__(256) void k_bscan(const int* __restrict__ gcnt_u,
                                               const int* __restrict__ gcnt_m,
                                               int nbu, int nbm, int E,
                                               int* __restrict__ boff_u, int* __restrict__ boff_m,
                                               int* __restrict__ gcur_u, int* __restrict__ gcur_m) {
  __shared__ int s[1024];
  for (int i = threadIdx.x; i < nbu; i += 256) s[i] = gcnt_u[i];
  for (int i = threadIdx.x; i < nbm; i += 256) s[512 + i] = gcnt_m[i];
  __syncthreads();
  if (threadIdx.x == 0) {
    int r = 0;
    for (int i = 0; i < nbu; ++i) { int v = s[i]; s[i] = r; r += v; }
  }
  if (threadIdx.x == 1) {
    int r = 0;
    for (int i = 0; i < nbm; ++i) { int v = s[512 + i]; s[512 + i] = r; r += v; }
  }
  __syncthreads();
  for (int i = threadIdx.x; i < nbu; i += 256) { boff_u[i] = s[i]; gcur_u[i] = s[i]; }
  for (int i = threadIdx.x; i < nbm; i += 256) { boff_m[i] = s[512 + i]; gcur_m[i] = s[512 + i]; }
  if (threadIdx.x == 0) { boff_u[nbu] = E; boff_m[nbm] = E; }
}

// ---------- phase 3: binning scatter into coarse buckets ----------
__global__ __launch_bounds__(256) void k_bscat(const int* __restrict__ esrc,
                                               const int* __restrict__ edst, int E,
                                               int* __restrict__ gcur_u, int* __restrict__ gcur_m,
                                               unsigned int* __restrict__ pk_u,
                                               unsigned int* __restrict__ pk_m,
                                               int nbu, int nbm, int nchunks) {
  extern __shared__ int sh2[];
  int dir = (blockIdx.x >= (unsigned)nchunks) ? 1 : 0;
  int chunk = dir ? (blockIdx.x - nchunks) : blockIdx.x;
  const int* key = dir ? edst : esrc;
  const int* pay = dir ? esrc : edst;
  int* gcur = dir ? gcur_m : gcur_u;
  unsigned int* pk = dir ? pk_m : pk_u;
  int nb = dir ? nbm : nbu;
  int* cnt = sh2;
  int* base = sh2 + nb;
  int beg = chunk * CH;
  int end = imin(beg + CH, E);
  for (int i = threadIdx.x; i < nb; i += 256) cnt[i] = 0;
  __syncthreads();
  for (int i = beg + threadIdx.x; i < end; i += 256) atomicAdd(&cnt[key[i] >> BSH], 1);
  __syncthreads();
  for (int i = threadIdx.x; i < nb; i += 256) {
    int c = cnt[i];
    base[i] = c ? atomicAdd(&gcur[i], c) : 0;
    cnt[i] = 0;
  }
  __syncthreads();
  for (int i = beg + threadIdx.x; i < end; i += 256) {
    int k = key[i];
    int b = k >> BSH;
    int r = atomicAdd(&cnt[b], 1);
    pk[base[b] + r] = ((unsigned)(k & (BSZ - 1)) << 18) | (unsigned)pay[i];
  }
}

// ---------- phase 4: per-bucket CSR build ----------
__global__ __launch_bounds__(512) void k_bbuild(const unsigned int* __restrict__ pk_u,
                                                const unsigned int* __restrict__ pk_m,
                                                const int* __restrict__ boff_u,
                                                const int* __restrict__ boff_m,
                                                int nbu, int nbm, int U_, int M_, int E,
                                                int* __restrict__ csr_u, int* __restrict__ csr_m,
                                                int* __restrict__ off_u, int* __restrict__ off_m) {
  __shared__ int hist[BSZ];
  __shared__ int cur[BSZ];
  int dir = (blockIdx.x >= (unsigned)nbu) ? 1 : 0;
  int b = dir ? (blockIdx.x - nbu) : blockIdx.x;
  const unsigned int* pk = dir ? pk_m : pk_u;
  const int* boff = dir ? boff_m : boff_u;
  int N = dir ? M_ : U_;
  int nb = dir ? nbm : nbu;
  int* csr = dir ? csr_m : csr_u;
  int* off = dir ? off_m : off_u;
  int beg = boff[b], end = boff[b + 1];
  int t = threadIdx.x;
  hist[t] = 0;
  __syncthreads();
  for (int i = beg + t; i < end; i += 512) atomicAdd(&hist[pk[i] >> 18], 1);
  __syncthreads();
  int v0 = hist[t];
  for (int o = 1; o < 512; o <<= 1) {
    int x = (t >= o) ? hist[t - o] : 0;
    __syncthreads();
    hist[t] += x;
    __syncthreads();
  }
  int excl = hist[t] - v0;
  cur[t] = excl;
  int node = (b << BSH) + t;
  if (node < N) off[node] = beg + excl;
  if (t == 0 && b == nb - 1) off[N] = E;
  __syncthreads();
  for (int i = beg + t; i < end; i += 512) {
    unsigned int p = pk[i];
    int n = (int)(p >> 18);
    int r = atomicAdd(&cur[n], 1);
    csr[beg + r] = (int)(p & 0x3FFFFu);
  }
}

// ---------- merged prep: movie projection + user cvt + combined classifier weights ----------
// R8: persistent blocks — proj path stages w_movie LDS ONCE per block then
// grid-strides over m (was: 25,000 blocks each re-staging 5 KB).
__global__ __launch_bounds__(256) void k_prep(
    const float* __restrict__ movie_x, const float* __restrict__ w_movie,
    const float* __restrict__ b_movie, const float* __restrict__ movie_emb,
    const int* __restrict__ mnid,
    const float* __restrict__ user_emb, const int* __restrict__ unid,
    const float* __restrict__ l2u_Wl, const float* __restrict__ l2u_Wr,
    const float* __restrict__ l2u_bl,
    const float* __restrict__ l2m_Wl, const float* __restrict__ l2m_Wr,
    const float* __restrict__ l2m_bl,
    const float* __restrict__ clsW,
    u16* __restrict__ xm_bf, u16* __restrict__ xu_bf, float* __restrict__ cw,
    int M_, int U_, int gProj, int gCvt) {
  __shared__ float ws_[F * H];
  int b = blockIdx.x;
  if (b < PBP) {
    for (int i = threadIdx.x; i < F * H; i += 256) ws_[i] = w_movie[i];
    __syncthreads();
    for (int blk = b; blk < gProj; blk += PBP) {
      int t = blk * 256 + threadIdx.x;
      int m = t >> 6;
      int h = t & 63;
      if (m < M_) {
        float acc = b_movie[h] + movie_emb[(size_t)mnid[m] * H + h];
        const float* xr = movie_x + (size_t)m * F;
        #pragma unroll
        for (int f = 0; f < F; ++f) acc += xr[f] * ws_[f * H + h];
        xm_bf[(size_t)m * H + h] = f2bf(acc);
      }
    }
  } else if (b < PBP + PBC) {
    for (int blk = b - PBP; blk < gCvt; blk += PBC) {
      int t = blk * 256 + threadIdx.x;
      if (t < U_ * 16) {
        int i = t >> 4;
        int g = t & 15;
        const float4 v = *(const float4*)(user_emb + (size_t)unid[i] * H + g * 4);
        ushort4 o;
        o.x = f2bf(v.x); o.y = f2bf(v.y); o.z = f2bf(v.z); o.w = f2bf(v.w);
        *(ushort4*)(xu_bf + (size_t)i * H + g * 4) = o;
      }
    }
  } else {
    int t = (b - PBP - PBC) * 256 + threadIdx.x;
    if (t < 448) {
      int k = t / C, c = t % C;
      float s = 0.f;
      for (int j = 0; j < H; ++j) s += l2u_Wl[k * H + j] * clsW[j * C + c];
      cw[t] = s;
    } else if (t < 896) {
      int u = t - 448; int k = u / C, c = u % C;
      float s = 0.f;
      for (int j = 0; j < H; ++j) s += l2u_Wr[k * H + j] * clsW[j * C + c];
      cw[t] = s;
    } else if (t < 1344) {
      int u = t - 896; int k = u / C, c = u % C;
      float s = 0.f;
      for (int j = 0; j < H; ++j) s += l2m_Wl[k * H + j] * clsW[(H + j) * C + c];
      cw[t] = s;
    } else if (t < 1792) {
      int u = t - 1344; int k = u / C, c = u % C;
      float s = 0.f;
      for (int j = 0; j < H; ++j) s += l2m_Wr[k * H + j] * clsW[(H + j) * C + c];
      cw[t] = s;
    } else if (t < 1799) {
      int c = t - 1792;
      float s = 0.f;
      for (int j = 0; j < H; ++j) s += l2u_bl[j] * clsW[j * C + c];
      cw[t] = s;
    } else if (t < 1806) {
      int c = t - 1799;
      float s = 0.f;
      for (int j = 0; j < H; ++j) s += l2m_bl[j] * clsW[(H + j) * C + c];
      cw[t] = s;
    } else if (t < 1870) {
      // zero row appended to movie bf16 table (index M_): out-of-range gather target
      xm_bf[(size_t)M_ * H + (t - 1806)] = 0;
    } else if (t < 1934) {
      // zero row appended to user bf16 table (index U_)
      xu_bf[(size_t)U_ * H + (t - 1870)] = 0;
    }
  }
}

// ---------- merged fused SAGE layer-1 (MFMA transform) + classifier projection ----------
// R6-proven config (86.9 us): LDS 57,856 (2 blocks/CU), launch_bounds(512,4), VGPR 52.
// Gather = TWO sequential 8-node groups with PER-GROUP wave-max (R7's merged variant
// regressed: joint max16 padding > per-group max8 padding; compiler already overlaps
// the two groups' loads).
__global__ __launch_bounds__(512, 4) void k_sage_mfma(
    const u16* __restrict__ xu, const u16* __restrict__ xm,
    const int* __restrict__ csr_u, const int* __restrict__ off_u,
    const int* __restrict__ csr_m, const int* __restrict__ off_m,
    const float* __restrict__ WlU, const float* __restrict__ blU, const float* __restrict__ WrU,
    const float* __restrict__ WlM, const float* __restrict__ blM, const float* __restrict__ WrM,
    const float* __restrict__ CWml, const float* __restrict__ CWur,   // user-side Z parts
    const float* __restrict__ CWul, const float* __restrict__ CWmr,   // movie-side Z parts
    u16* __restrict__ Zau, u16* __restrict__ Zru,
    u16* __restrict__ Zam, u16* __restrict__ Zrm,
    int U_, int M_, int E_, int gU) {
  __shared__ int sWl[64 * 36];
  __shared__ int sWr[64 * 36];
  __shared__ int sAggHi[128 * 36];
  __shared__ int sAggLo[128 * 36];
  __shared__ int sCC[16 * 36];
  __shared__ float sBl[64];

  int movie = (blockIdx.x >= (unsigned)gU) ? 1 : 0;
  int bside = movie ? (blockIdx.x - gU) : blockIdx.x;
  const u16* srcT = movie ? xu : xm;
  const u16* rootT = movie ? xm : xu;
  const int* csr = movie ? csr_m : csr_u;
  const int* off = movie ? off_m : off_u;
  const float* Wl = movie ? WlM : WlU;
  const float* Wr = movie ? WrM : WrU;
  const float* bl = movie ? blM : blU;
  const float* CWl = movie ? CWul : CWml;
  const float* CWr = movie ? CWmr : CWur;
  u16* Za = movie ? Zam : Zau;
  u16* Zr = movie ? Zrm : Zru;
  int N = movie ? M_ : U_;
  int zrow = movie ? U_ : M_;        // index of the all-zero row in srcT

  int tid = threadIdx.x;
  // stage weights: W^T as bf16 pairs (row j, 32 dwords + 4 pad)
  for (int idx = tid; idx < 2048; idx += 512) {
    int j = idx & 63, kk = idx >> 6;
    sWl[j * 36 + kk] = pack2bf(Wl[(2 * kk) * H + j], Wl[(2 * kk + 1) * H + j]);
    sWr[j * 36 + kk] = pack2bf(Wr[(2 * kk) * H + j], Wr[(2 * kk + 1) * H + j]);
  }
  // stage combined classifier matrix CC[j][cc] (bf16 pairs along j), B-fragment layout
  for (int idx = tid; idx < 512; idx += 512) {
    int cc = idx >> 5, kk = idx & 31;
    float f0, f1;
    if (cc < 7)       { f0 = CWl[(2 * kk) * C + cc];     f1 = CWl[(2 * kk + 1) * C + cc]; }
    else if (cc == 7) { f0 = 0.f; f1 = 0.f; }
    else if (cc < 15) { f0 = CWr[(2 * kk) * C + cc - 8]; f1 = CWr[(2 * kk + 1) * C + cc - 8]; }
    else              { f0 = 0.f; f1 = 0.f; }
    sCC[cc * 36 + kk] = pack2bf(f0, f1);
  }
  if (tid < 64) sBl[tid] = bl[tid];
  __syncthreads();

  int lane = tid & 63;
  int wid = tid >> 6;
  int slot = lane >> 3;      // 0..7: node within group
  int l3 = lane & 7;         // 0..7: column-octet within row
  int sbase = slot * 8;
  int node0 = bside * 128 + wid * 16;

  // ---- gather phase: 2 groups of 8 nodes; per-node-slot dwordx4 accumulation ----
  #pragma unroll
  for (int g = 0; g < 2; ++g) {
    int n = node0 + g * 8 + slot;
    int nc = n < N ? n : N - 1;
    int jb = off[nc];
    int d = off[nc + 1] - jb;
    if (n >= N) d = 0;
    int dmax = d;
    dmax = imax(dmax, __shfl_xor(dmax, 8));
    dmax = imax(dmax, __shfl_xor(dmax, 16));
    dmax = imax(dmax, __shfl_xor(dmax, 32));

    f32x2 acc2[4] = {{0.f, 0.f}, {0.f, 0.f}, {0.f, 0.f}, {0.f, 0.f}};
    for (int tb = 0; tb < dmax; tb += 8) {
      int idx = tb + l3;
      int ci = imin(jb + idx, E_ - 1);
      int e = (idx < d) ? csr[ci] : zrow;   // invalid neighbor -> zero row
      uint4 v[8];
      #pragma unroll
      for (int k = 0; k < 8; ++k) {
        int a = __shfl(e, sbase + k);
        v[k] = *(const uint4*)(srcT + (size_t)(unsigned)a * H + l3 * 8);
      }
      #pragma unroll
      for (int k = 0; k < 8; ++k) {
        f32x2 p0 = {lo16f(v[k].x), hi16f(v[k].x)};
        f32x2 p1 = {lo16f(v[k].y), hi16f(v[k].y)};
        f32x2 p2 = {lo16f(v[k].z), hi16f(v[k].z)};
        f32x2 p3 = {lo16f(v[k].w), hi16f(v[k].w)};
        acc2[0] += p0; acc2[1] += p1; acc2[2] += p2; acc2[3] += p3;
      }
    }

    // finalize: mean, hi/lo bf16 split via v_cvt_pk, b128 LDS store
    float inv = 1.0f / (float)imax(d, 1);
    int hi4[4], lo4[4];
    #pragma unroll
    for (int pp = 0; pp < 4; ++pp) {
      float s0 = acc2[pp].x * inv;
      float s1 = acc2[pp].y * inv;
      int w = cvtpk_bf16(s0, s1);
      float r0 = s0 - lo16f((unsigned)w);
      float r1 = s1 - hi16f((unsigned)w);
      hi4[pp] = w;
      lo4[pp] = cvtpk_bf16(r0, r1);
    }
    int row = wid * 16 + g * 8 + slot;
    *(int4*)&sAggHi[row * 36 + l3 * 4] = *(int4*)hi4;
    *(int4*)&sAggLo[row * 36 + l3 * 4] = *(int4*)lo4;
  }
  // per-wave region: wave reads only its own writes; in-wave LDS ordering suffices

  // ---- MFMA transform phase ----
  int r16 = lane & 15;
  int q4 = lane >> 4;
  union FU { int4 i; bf16x8 b; };
  FU ahi[2], alo[2], art[2];
  int arow = wid * 16 + r16;
  int rnode = node0 + r16;
  rnode = rnode < N ? rnode : N - 1;
  #pragma unroll
  for (int kt = 0; kt < 2; ++kt) {
    ahi[kt].i = *(const int4*)&sAggHi[arow * 36 + kt * 16 + q4 * 4];
    alo[kt].i = *(const int4*)&sAggLo[arow * 36 + kt * 16 + q4 * 4];
    art[kt].i = ((const int4*)(rootT + (size_t)rnode * H))[kt * 4 + q4];
  }

  // sAggHi rows of THIS wave are dead once ahi/alo are in registers: reuse them as the
  // relayout buffer valT[16 nodes][64 j] (u16, row stride 72 = 36 dwords, 2-way banks).
  u16* sVT = (u16*)(sAggHi + (size_t)wid * 16 * 36);
  const int* sVTd = sAggHi + (size_t)wid * 16 * 36;

  #pragma unroll
  for (int t = 0; t < 4; ++t) {
    f32x4 cacc = {0.f, 0.f, 0.f, 0.f};
    #pragma unroll
    for (int kt = 0; kt < 2; ++kt) {
      FU bwl, bwr;
      bwl.i = *(const int4*)&sWl[(t * 16 + r16) * 36 + kt * 16 + q4 * 4];
      bwr.i = *(const int4*)&sWr[(t * 16 + r16) * 36 + kt * 16 + q4 * 4];
      cacc = __builtin_amdgcn_mfma_f32_16x16x32_bf16(ahi[kt].b, bwl.b, cacc, 0, 0, 0);
      cacc = __builtin_amdgcn_mfma_f32_16x16x32_bf16(alo[kt].b, bwl.b, cacc, 0, 0, 0);
      cacc = __builtin_amdgcn_mfma_f32_16x16x32_bf16(art[kt].b, bwr.b, cacc, 0, 0, 0);
    }
    float bj = sBl[t * 16 + r16];
    float v0 = fmaxf(cacc[0] + bj, 0.f);
    float v1 = fmaxf(cacc[1] + bj, 0.f);
    float v2 = fmaxf(cacc[2] + bj, 0.f);
    float v3 = fmaxf(cacc[3] + bj, 0.f);
    // relu'd H_out[node=q4*4+r][j=t*16+r16] -> valT[node][j] (A-fragment layout)
    int w01 = cvtpk_bf16(v0, v1);
    int w23 = cvtpk_bf16(v2, v3);
    int base = (q4 * 4) * 72 + t * 16 + r16;
    sVT[base]       = (u16)w01;
    sVT[base + 72]  = (u16)((unsigned)w01 >> 16);
    sVT[base + 144] = (u16)w23;
    sVT[base + 216] = (u16)((unsigned)w23 >> 16);
  }

  // ---- classifier projection as a second MFMA: Z[16 nodes][16 cc] = valT @ CC ----
  f32x4 z4 = {0.f, 0.f, 0.f, 0.f};
  #pragma unroll
  for (int kt = 0; kt < 2; ++kt) {
    FU a2, b2;
    a2.i = *(const int4*)&sVTd[r16 * 36 + kt * 16 + q4 * 4];
    b2.i = *(const int4*)&sCC[r16 * 36 + kt * 16 + q4 * 4];
    z4 = __builtin_amdgcn_mfma_f32_16x16x32_bf16(a2.b, b2.b, z4, 0, 0, 0);
  }

  // ---- coalesced split-Z write: transpose through LDS (this wave's sAggLo is dead)
  // ztile[16 nodes][16 cc] u16; lanes 0..15 store Za rows (int4), 16..31 store Zr.
  u16* zt = (u16*)(sAggLo + (size_t)wid * 16 * 36);
  #pragma unroll
  for (int r = 0; r < 4; ++r) zt[(q4 * 4 + r) * 16 + r16] = f2bf(z4[r]);
  if (lane < 32) {
    int nodeL = lane & 15;
    int half = lane >> 4;          // 0: Za (cols 0..7), 1: Zr (cols 8..15)
    int node = node0 + nodeL;
    if (node < N) {
      int4 zi = *(const int4*)&zt[nodeL * 16 + half * 8];
      u16* Zq = half ? Zr : Za;
      *(int4*)&Zq[(size_t)node * 8] = zi;
    }
  }
}

// ---------- merged layer-2 aggregation in projected bf16 space ----------
// Z split into 16 B aggregate/root rows halves the random-gather volume.
static __device__ __forceinline__ void accz8(float* acc, uint4 zv) {
  acc[0] += lo16f(zv.x); acc[1] += hi16f(zv.x);
  acc[2] += lo16f(zv.y); acc[3] += hi16f(zv.y);
  acc[4] += lo16f(zv.z); acc[5] += hi16f(zv.z);
  acc[6] += lo16f(zv.w); acc[7] += hi16f(zv.w);
}

__global__ __launch_bounds__(256) void k_agg7m(
    const u16* __restrict__ Zau, const u16* __restrict__ Zru,
    const u16* __restrict__ Zam, const u16* __restrict__ Zrm,
    const int* __restrict__ csr_u, const int* __restrict__ off_u,
    const int* __restrict__ csr_m, const int* __restrict__ off_m,
    const float* __restrict__ cbu, const float* __restrict__ cbm,
    float* __restrict__ Pu, float* __restrict__ Pm,
    int U_, int M_, int gU) {
  int movie = (blockIdx.x >= (unsigned)gU) ? 1 : 0;
  int bside = movie ? (blockIdx.x - gU) : blockIdx.x;
  const u16* Zsrc = movie ? Zau : Zam;   // aggregate part of opposite side
  const u16* Zroot = movie ? Zrm : Zru;  // root part of own side
  const int* csr = movie ? csr_m : csr_u;
  const int* off = movie ? off_m : off_u;
  const float* cb = movie ? cbm : cbu;
  float* P = movie ? Pm : Pu;
  int N = movie ? M_ : U_;

  int n = bside * 256 + threadIdx.x;
  if (n >= N) return;
  int beg = off[n], end = off[n + 1];
  float acc[8] = {0.f, 0.f, 0.f, 0.f, 0.f, 0.f, 0.f, 0.f};
  int j = beg;
  for (; j + 4 <= end; j += 4) {
    int a0 = csr[j], a1 = csr[j + 1], a2 = csr[j + 2], a3 = csr[j + 3];
    uint4 z0 = *(const uint4*)(Zsrc + (size_t)a0 * 8);
    uint4 z1 = *(const uint4*)(Zsrc + (size_t)a1 * 8);
    uint4 z2 = *(const uint4*)(Zsrc + (size_t)a2 * 8);
    uint4 z3 = *(const uint4*)(Zsrc + (size_t)a3 * 8);
    accz8(acc, z0); accz8(acc, z1); accz8(acc, z2); accz8(acc, z3);
  }
  for (; j < end; ++j) {
    uint4 zv = *(const uint4*)(Zsrc + (size_t)csr[j] * 8);
    accz8(acc, zv);
  }
  float inv = 1.f / (float)imax(end - beg, 1);
  uint4 zr = *(const uint4*)(Zroot + (size_t)n * 8);
  float4 o0, o1;
  o0.x = acc[0] * inv + lo16f(zr.x) + cb[0];
  o0.y = acc[1] * inv + hi16f(zr.x) + cb[1];
  o0.z = acc[2] * inv + lo16f(zr.y) + cb[2];
  o0.w = acc[3] * inv + hi16f(zr.y) + cb[3];
  o1.x = acc[4] * inv + lo16f(zr.z) + cb[4];
  o1.y = acc[5] * inv + hi16f(zr.z) + cb[5];
  o1.z = acc[6] * inv + lo16f(zr.w) + cb[6];
  o1.w = 0.f;
  float4* po = (float4*)(P + (size_t)n * 8);
  po[0] = o0;
  po[1] = o1;
}

// ---------- final edge classifier: one thread per edge ----------
__global__ __launch_bounds__(256) void k_final(const int* __restrict__ els,
                                               const int* __restrict__ eld,
                                               const float* __restrict__ Pu,
                                               const float* __restrict__ Pm,
                                               const float* __restrict__ clsb,
                                               float* __restrict__ out, int EL_) {
  int e = blockIdx.x * 256 + threadIdx.x;
  if (e >= EL_) return;
  int su = els[e], sm = eld[e];
  const float4* pu = (const float4*)(Pu + (size_t)su * 8);
  const float4* pm = (const float4*)(Pm + (size_t)sm * 8);
  float4 u0 = pu[0], u1 = pu[1];
  float4 m0 = pm[0], m1 = pm[1];
  float* po = out + (size_t)e * C;
  po[0] = u0.x + m0.x + clsb[0];
  po[1] = u0.y + m0.y + clsb[1];
  po[2] = u0.z + m0.z + clsb[2];
  po[3] = u0.w + m0.w + clsb[3];
  po[4] = u1.x + m1.x + clsb[4];
  po[5] = u1.y + m1.y + clsb[5];
  po[6] = u1.z + m1.z + clsb[6];
}

extern "C" void kernel_launch(void* const* d_in, const int* in_sizes, int n_in,
                              void* d_out, int out_size, void* d_ws, size_t ws_size,
                              hipStream_t stream) {
  (void)n_in; (void)out_size; (void)ws_size;
  const int*   unid      = (const int*)d_in[0];
  const int*   mnid      = (const int*)d_in[1];
  const float* movie_x   = (const float*)d_in[2];
  const int*   e_src     = (const int*)d_in[3];
  const int*   e_dst     = (const int*)d_in[4];
  const int*   el_src    = (const int*)d_in[5];
  const int*   el_dst    = (const int*)d_in[6];
  const float* user_emb  = (const float*)d_in[7];
  const float* movie_emb = (const float*)d_in[8];
  const float* w_movie   = (const float*)d_in[9];
  const float* b_movie   = (const float*)d_in[10];
  const float* l1r_Wl    = (const float*)d_in[11];
  const float* l1r_bl    = (const float*)d_in[12];
  const float* l1r_Wr    = (const float*)d_in[13];
  const float* l1v_Wl    = (const float*)d_in[14];
  const float* l1v_bl    = (const float*)d_in[15];
  const float* l1v_Wr    = (const float*)d_in[16];
  const float* l2r_Wl    = (const float*)d_in[17];
  const float* l2r_bl    = (const float*)d_in[18];
  const float* l2r_Wr    = (const float*)d_in[19];
  const float* l2v_Wl    = (const float*)d_in[20];
  const float* l2v_bl    = (const float*)d_in[21];
  const float* l2v_Wr    = (const float*)d_in[22];
  const float* cls_W     = (const float*)d_in[23];
  const float* cls_b     = (const float*)d_in[24];

  int U  = in_sizes[0];
  int M  = in_sizes[1];
  int E  = in_sizes[3];
  int EL = in_sizes[5];

  int nbu = (U + BSZ - 1) / BSZ;
  int nbm = (M + BSZ - 1) / BSZ;
  int nchunks = (E + CH - 1) / CH;

  char* p = (char*)d_ws;
  auto alloc = [&](size_t nbytes) { char* r = p; p += (nbytes + 255) & ~(size_t)255; return r; };

  u16*   xm_bf  = (u16*)alloc((size_t)(M + 1) * H * 2);   // +1: zero row for invalid gathers
  u16*   xu_bf  = (u16*)alloc((size_t)(U + 1) * H * 2);   // +1: zero row
  u16*   Zau    = (u16*)alloc((size_t)U * 8 * 2);
  u16*   Zru    = (u16*)alloc((size_t)U * 8 * 2);
  u16*   Zam    = (u16*)alloc((size_t)M * 8 * 2);
  u16*   Zrm    = (u16*)alloc((size_t)M * 8 * 2);
  float* Pu     = (float*)alloc((size_t)U * 8 * 4);
  float* Pm     = (float*)alloc((size_t)M * 8 * 4);
  int*   csr_u  = (int*)alloc((size_t)E * 4);
  int*   csr_m  = (int*)alloc((size_t)E * 4);
  int*   off_u  = (int*)alloc((size_t)(U + 1) * 4);
  int*   off_m  = (int*)alloc((size_t)(M + 1) * 4);
  unsigned int* pk_u = (unsigned int*)alloc((size_t)E * 4);
  unsigned int* pk_m = (unsigned int*)alloc((size_t)E * 4);
  int*   gcnt   = (int*)alloc((size_t)(nbu + nbm) * 4);
  int*   gcnt_u = gcnt;
  int*   gcnt_m = gcnt + nbu;
  int*   boff_u = (int*)alloc((size_t)(nbu + 1) * 4);
  int*   boff_m = (int*)alloc((size_t)(nbm + 1) * 4);
  int*   gcur_u = (int*)alloc((size_t)nbu * 4);
  int*   gcur_m = (int*)alloc((size_t)nbm * 4);
  float* cw     = (float*)alloc(1806 * 4);
  float* CWul = cw, *CWur = cw + 448, *CWml = cw + 896, *CWmr = cw + 1344;
  float* cbu  = cw + 1792, *cbm = cw + 1799;

  hipMemsetAsync(gcnt, 0, (size_t)(nbu + nbm) * 4, stream);

  // ---- CSR build ----
  k_bhist<<<256, 256, (size_t)(nbu + nbm) * 4, stream>>>(e_src, e_dst, E, gcnt_u, gcnt_m, nbu, nbm);
  k_bscan<<<1, 256, 0, stream>>>(gcnt_u, gcnt_m, nbu, nbm, E, boff_u, boff_m, gcur_u, gcur_m);
  k_bscat<<<2 * nchunks, 256, (size_t)(2 * nbu) * 4, stream>>>(e_src, e_dst, E, gcur_u, gcur_m,
                                                               pk_u, pk_m, nbu, nbm, nchunks);
  k_bbuild<<<nbu + nbm, 512, 0, stream>>>(pk_u, pk_m, boff_u, boff_m, nbu, nbm, U, M, E,
                                          csr_u, csr_m, off_u, off_m);

  // ---- merged prep (persistent blocks; bf16 tables + zero rows + classifier weights) ----
  int gProj = (M * H + 255) / 256;
  int gCvt  = (U * 16 + 255) / 256;
  k_prep<<<PBP + PBC + 8, 256, 0, stream>>>(
      movie_x, w_movie, b_movie, movie_emb, mnid, user_emb, unid,
      l2v_Wl, l2v_Wr, l2v_bl, l2r_Wl, l2r_Wr, l2r_bl, cls_W,
      xm_bf, xu_bf, cw, M, U, gProj, gCvt);

  // ---- merged layer-1 (MFMA) fused with classifier projection ----
  int gU_s = (U + 127) / 128;
  int gM_s = (M + 127) / 128;
  k_sage_mfma<<<gU_s + gM_s, 512, 0, stream>>>(
      xu_bf, xm_bf, csr_u, off_u, csr_m, off_m,
      l1v_Wl, l1v_bl, l1v_Wr,
      l1r_Wl, l1r_bl, l1r_Wr,
      CWml, CWur, CWul, CWmr,
      Zau, Zru, Zam, Zrm, U, M, E, gU_s);

  // ---- merged layer-2 aggregation ----
  int gU_a = (U + 255) / 256;
  int gM_a = (M + 255) / 256;
  k_agg7m<<<gU_a + gM_a, 256, 0, stream>>>(Zau, Zru, Zam, Zrm, csr_u, off_u, csr_m, off_m,
                                           cbu, cbm, Pu, Pm, U, M, gU_a);

  // ---- final ----
  k_final<<<(EL + 255) / 256, 256, 0, stream>>>(el_src, el_dst, Pu, Pm, cls_b, (float*)d_out, EL);
}